// Round 4
// baseline (1342.230 us; speedup 1.0000x reference)
//
#include <hip/hip_runtime.h>

#define HIDDEN 450
#define MAX_NB 15
#define N_ATOMS 20000
#define N_BONDS 40000
#define N_MESS  16000
#define N_MOLS  1000
#define KPAD    512     // padded concat-K: [feat 0..39 | nei 40..489 | pad]
#define MSTRIDE 456     // message row stride = 912B = 57 x 16B chunks
#define LPAD    72      // LDS tile row stride (elements): 144B = 36 banks

typedef unsigned int uint;
typedef unsigned short ushort;
typedef __bf16 bf16x8 __attribute__((ext_vector_type(8)));
typedef float  f32x4  __attribute__((ext_vector_type(4)));

__device__ __forceinline__ ushort f2bf(float f) {
    uint u = __builtin_bit_cast(uint, f);
    u += 0x7fffu + ((u >> 16) & 1u);     // RNE
    return (ushort)(u >> 16);
}
__device__ __forceinline__ float bfhi(uint w) {
    return __builtin_bit_cast(float, w & 0xffff0000u);
}
__device__ __forceinline__ float bflo(uint w) {
    return __builtin_bit_cast(float, w << 16);
}

// ---------------- pack kernels (run once per launch) ----------------

__global__ __launch_bounds__(256) void pack_tree(const float* __restrict__ tree,
                                                 ushort* __restrict__ tbuf) {
    const int r = blockIdx.x, t = threadIdx.x;
    if (t < 228) {
        uint p = 0;
        if (t < 225) {
            const float2 v = *(const float2*)&tree[(size_t)r * HIDDEN + 2 * t];
            p = (uint)f2bf(v.x) | ((uint)f2bf(v.y) << 16);
        }
        ((uint*)(tbuf + (size_t)r * MSTRIDE))[t] = p;
    }
}

__global__ __launch_bounds__(256) void pack_bonds(const float* __restrict__ fbonds,
                                                  ushort* __restrict__ Abuf) {
    const int r = blockIdx.x * 4 + (threadIdx.x >> 6);
    const int t = threadIdx.x & 63;
    if (r >= N_BONDS) return;
    ushort* row = Abuf + (size_t)r * KPAD;
    if (t < 40) row[t] = f2bf(fbonds[(size_t)r * 40 + t]);
    else        row[t] = 0;                    // cols 40..63 zero (first GEMM K=64)
    if (t < 16) row[496 + t] = 0;              // cols 496..511 zero
}

__global__ __launch_bounds__(256) void pack_atoms(const float* __restrict__ fatoms,
                                                  ushort* __restrict__ Aout) {
    const int r = blockIdx.x * 4 + (threadIdx.x >> 6);
    const int t = threadIdx.x & 63;
    if (r >= N_ATOMS) return;
    ushort* row = Aout + (size_t)r * KPAD;
    if (t < 40) row[t] = (t < 35) ? f2bf(fatoms[(size_t)r * 35 + t]) : (ushort)0;
    if (t < 16) row[496 + t] = 0;              // cols 496..511 zero
}

__global__ __launch_bounds__(256) void pack_w(const float* __restrict__ W_i,
                                              const float* __restrict__ W_h,
                                              const float* __restrict__ W_o,
                                              ushort* __restrict__ Wcat,
                                              ushort* __restrict__ Wocat) {
    const int n = blockIdx.x;  // 0..511
    for (int c = threadIdx.x; c < KPAD; c += 256) {
        float v = 0.0f, vo = 0.0f;
        if (n < HIDDEN) {
            if (c < 40)       v = W_i[(size_t)n * 40 + c];
            else if (c < 490) v = W_h[(size_t)n * HIDDEN + (c - 40)];
            if (c < 35)       vo = W_o[(size_t)n * 485 + c];
            else if (c >= 40 && c < 490) vo = W_o[(size_t)n * 485 + 35 + (c - 40)];
        }
        Wcat [(size_t)n * KPAD + c] = f2bf(v);
        Wocat[(size_t)n * KPAD + c] = f2bf(vo);
    }
}

// ---------------- gather: dst[r, 40..495] = sum_j concat(tree,gmsg)[g[r,j]] -------
__global__ __launch_bounds__(256) void gather_sum(const int* __restrict__ g,
                                                  const ushort* __restrict__ tbuf,
                                                  const ushort* __restrict__ gmsg,
                                                  ushort* __restrict__ dst, int nrows) {
    const int r = blockIdx.x * 4 + (threadIdx.x >> 6);
    const int lane = threadIdx.x & 63;
    if (r >= nrows) return;
    const int* gr = g + (size_t)r * MAX_NB;
    int idx[MAX_NB];
#pragma unroll
    for (int j = 0; j < MAX_NB; ++j) idx[j] = gr[j];
    if (lane >= 57) return;
    const int off = lane * 8;
    float acc[8] = {};
#pragma unroll
    for (int j = 0; j < MAX_NB; ++j) {
        const ushort* row = (idx[j] < N_MESS)
            ? tbuf + (size_t)idx[j] * MSTRIDE
            : gmsg + (size_t)(idx[j] - N_MESS) * MSTRIDE;
        const uint4 w = *(const uint4*)(row + off);
        acc[0] += bflo(w.x); acc[1] += bfhi(w.x);
        acc[2] += bflo(w.y); acc[3] += bfhi(w.y);
        acc[4] += bflo(w.z); acc[5] += bfhi(w.z);
        acc[6] += bflo(w.w); acc[7] += bfhi(w.w);
    }
    uint4 p;
    p.x = (uint)f2bf(acc[0]) | ((uint)f2bf(acc[1]) << 16);
    p.y = (uint)f2bf(acc[2]) | ((uint)f2bf(acc[3]) << 16);
    p.z = (uint)f2bf(acc[4]) | ((uint)f2bf(acc[5]) << 16);
    p.w = (uint)f2bf(acc[6]) | ((uint)f2bf(acc[7]) << 16);
    *(uint4*)(dst + (size_t)r * KPAD + 40 + off) = p;
}

// ---------------- MFMA GEMM, register-pipelined staging ----------------
// C[M x 450] = relu(A[M x K] · W[450 x K]^T (+bias))
// MODE 0: bf16 store to gmsg (+ zero pad cols). MODE 1: f32 atomicAdd to out.
// grid = (n_tiles=4, m_tiles); block = 256 = 4 waves (2x2 of 64x64).
template <int MODE>
__global__ __launch_bounds__(256, 3) void mfma_gemm(
    const ushort* __restrict__ A, int M,
    const ushort* __restrict__ W, int K,
    const float* __restrict__ bias, const int* __restrict__ mol_ids,
    ushort* __restrict__ gout, float* __restrict__ aout) {
    __shared__ ushort At[128 * LPAD];
    __shared__ ushort Wt[128 * LPAD];
    const int tid  = threadIdx.x;
    const int lane = tid & 63;
    const int wave = tid >> 6;
    const int wm = (wave >> 1) * 64;
    const int wn = (wave & 1) * 64;
    const int m0 = blockIdx.y * 128;
    const int n0 = blockIdx.x * 128;

    // staging: thread t owns row t>>1 (of 128), 32-elem half (t&1) of BK=64
    const int srow = tid >> 1;
    const int scol = (tid & 1) * 32;
    const size_t gA = (size_t)min(m0 + srow, M - 1) * KPAD + scol;
    const size_t gW = (size_t)(n0 + srow) * KPAD + scol;
    const int lds_off = srow * LPAD + scol;

    f32x4 acc[4][4];
#pragma unroll
    for (int i = 0; i < 4; ++i)
#pragma unroll
        for (int j = 0; j < 4; ++j) acc[i][j] = (f32x4){0.f, 0.f, 0.f, 0.f};

    uint4 pa[2], pw[2];   // 32 elements each matrix = 2x16B... (4x8 elems)
    uint4 pa2[2], pw2[2];
#pragma unroll
    for (int c = 0; c < 2; ++c) {
        pa[c]  = *(const uint4*)&A[gA + c * 8];
        pa2[c] = *(const uint4*)&A[gA + 16 + c * 8];
        pw[c]  = *(const uint4*)&W[gW + c * 8];
        pw2[c] = *(const uint4*)&W[gW + 16 + c * 8];
    }

    const int lr = lane & 15;
    const int lk = lane >> 4;

#pragma unroll 1
    for (int k0 = 0; k0 < K; k0 += 64) {
        // commit prefetched tile to LDS (compiler waits vmcnt here)
#pragma unroll
        for (int c = 0; c < 2; ++c) {
            *(uint4*)&At[lds_off + c * 8]      = pa[c];
            *(uint4*)&At[lds_off + 16 + c * 8] = pa2[c];
            *(uint4*)&Wt[lds_off + c * 8]      = pw[c];
            *(uint4*)&Wt[lds_off + 16 + c * 8] = pw2[c];
        }
        __syncthreads();

        // prefetch next tile (stays in flight through the compute phase)
        if (k0 + 64 < K) {
            const size_t a = gA + k0 + 64, w = gW + k0 + 64;
#pragma unroll
            for (int c = 0; c < 2; ++c) {
                pa[c]  = *(const uint4*)&A[a + c * 8];
                pa2[c] = *(const uint4*)&A[a + 16 + c * 8];
                pw[c]  = *(const uint4*)&W[w + c * 8];
                pw2[c] = *(const uint4*)&W[w + 16 + c * 8];
            }
        }

        // compute BK=64 (two k-halves of 32)
#pragma unroll
        for (int h = 0; h < 2; ++h) {
            bf16x8 af[4], wf[4];
#pragma unroll
            for (int s = 0; s < 4; ++s)
                af[s] = *(const bf16x8*)&At[(wm + s * 16 + lr) * LPAD + h * 32 + lk * 8];
#pragma unroll
            for (int s = 0; s < 4; ++s)
                wf[s] = *(const bf16x8*)&Wt[(wn + s * 16 + lr) * LPAD + h * 32 + lk * 8];
#pragma unroll
            for (int mt = 0; mt < 4; ++mt)
#pragma unroll
                for (int nt = 0; nt < 4; ++nt)
                    acc[mt][nt] = __builtin_amdgcn_mfma_f32_16x16x32_bf16(
                        af[mt], wf[nt], acc[mt][nt], 0, 0, 0);
        }
        // raw barrier: no vmcnt fence -> prefetch loads survive into next iter
        __builtin_amdgcn_s_barrier();
    }

    const int col_l = lane & 15;
    const int rbase = (lane >> 4) * 4;
#pragma unroll
    for (int mt = 0; mt < 4; ++mt) {
#pragma unroll
        for (int nt = 0; nt < 4; ++nt) {
            const int n = n0 + wn + nt * 16 + col_l;
#pragma unroll
            for (int reg = 0; reg < 4; ++reg) {
                const int m = m0 + wm + mt * 16 + rbase + reg;
                if (m >= M) continue;
                float v = acc[mt][nt][reg];
                if (MODE == 0) {
                    if (n < HIDDEN)
                        gout[(size_t)m * MSTRIDE + n] = f2bf(fmaxf(v, 0.0f));
                    else if (n < MSTRIDE)
                        gout[(size_t)m * MSTRIDE + n] = 0;  // keep pad cols zero
                } else {
                    if (n < HIDDEN) {
                        v = fmaxf(v + bias[n], 0.0f);
                        atomicAdd(&aout[(size_t)mol_ids[m] * HIDDEN + n], v);
                    }
                }
            }
        }
    }
}

// ---------------- molecule mean ----------------
__global__ __launch_bounds__(256) void count_atoms(const int* __restrict__ mol_ids,
                                                   float* __restrict__ counts) {
    const int a = blockIdx.x * 256 + threadIdx.x;
    if (a < N_ATOMS) atomicAdd(&counts[mol_ids[a]], 1.0f);
}
__global__ __launch_bounds__(256) void div_counts(float* __restrict__ out,
                                                  const float* __restrict__ counts) {
    const int i = blockIdx.x * 256 + threadIdx.x;
    if (i < N_MOLS * HIDDEN) out[i] = out[i] / counts[i / HIDDEN];
}

extern "C" void kernel_launch(void* const* d_in, const int* in_sizes, int n_in,
                              void* d_out, int out_size, void* d_ws, size_t ws_size,
                              hipStream_t stream) {
    const float* fatoms  = (const float*)d_in[0];
    const float* fbonds  = (const float*)d_in[1];
    const int*   agraph  = (const int*)d_in[2];
    const int*   bgraph  = (const int*)d_in[3];
    const int*   mol_ids = (const int*)d_in[4];
    const float* tree    = (const float*)d_in[6];
    const float* W_i     = (const float*)d_in[7];
    const float* W_h     = (const float*)d_in[8];
    const float* W_o     = (const float*)d_in[9];
    const float* b_o     = (const float*)d_in[10];
    float* out = (float*)d_out;

    ushort* Abuf  = (ushort*)d_ws;                       // 40000 x 512
    ushort* Aout  = Abuf  + (size_t)N_BONDS * KPAD;      // 20000 x 512
    ushort* gmsg  = Aout  + (size_t)N_ATOMS * KPAD;      // 40000 x 456
    ushort* tbuf  = gmsg  + (size_t)N_BONDS * MSTRIDE;   // 16000 x 456
    ushort* Wcat  = tbuf  + (size_t)N_MESS  * MSTRIDE;   // 512 x 512
    ushort* Wocat = Wcat  + (size_t)KPAD * KPAD;         // 512 x 512
    float*  counts = (float*)(Wocat + (size_t)KPAD * KPAD);

    (void)hipMemsetAsync(d_out, 0, (size_t)N_MOLS * HIDDEN * sizeof(float), stream);
    (void)hipMemsetAsync(counts, 0, N_MOLS * sizeof(float), stream);

    const dim3 blk(256);
    pack_tree <<<N_MESS, blk, 0, stream>>>(tree, tbuf);
    pack_bonds<<<(N_BONDS + 3) / 4, blk, 0, stream>>>(fbonds, Abuf);
    pack_atoms<<<(N_ATOMS + 3) / 4, blk, 0, stream>>>(fatoms, Aout);
    pack_w    <<<KPAD, blk, 0, stream>>>(W_i, W_h, W_o, Wcat, Wocat);

    const dim3 gB(4, (N_BONDS + 127) / 128);   // x = n-tile: A-sharing blocks adjacent
    const dim3 gA(4, (N_ATOMS + 127) / 128);

    // gmsg = relu(fbonds @ W_i^T): nei cols 40..63 are zero, so K=64 suffices
    mfma_gemm<0><<<gB, blk, 0, stream>>>(Abuf, N_BONDS, Wcat, 64,
                                         nullptr, nullptr, gmsg, nullptr);
    for (int it = 0; it < 5; ++it) {
        gather_sum<<<(N_BONDS + 3) / 4, blk, 0, stream>>>(bgraph, tbuf, gmsg,
                                                          Abuf, N_BONDS);
        mfma_gemm<0><<<gB, blk, 0, stream>>>(Abuf, N_BONDS, Wcat, KPAD,
                                             nullptr, nullptr, gmsg, nullptr);
    }
    gather_sum<<<(N_ATOMS + 3) / 4, blk, 0, stream>>>(agraph, tbuf, gmsg,
                                                      Aout, N_ATOMS);
    mfma_gemm<1><<<gA, blk, 0, stream>>>(Aout, N_ATOMS, Wocat, KPAD,
                                         b_o, mol_ids, nullptr, out);

    count_atoms<<<(N_ATOMS + 255) / 256, blk, 0, stream>>>(mol_ids, counts);
    div_counts <<<(N_MOLS * HIDDEN + 255) / 256, blk, 0, stream>>>(out, counts);
}

// Round 5
// 1128.767 us; speedup vs baseline: 1.1891x; 1.1891x over previous
//
#include <hip/hip_runtime.h>

#define HIDDEN 450
#define MAX_NB 15
#define N_ATOMS 20000
#define N_BONDS 40000
#define N_MESS  16000
#define N_MOLS  1000
#define KPAD    512     // padded concat-K: [feat 0..39 | nei 40..489 | pad]
#define MSTRIDE 456     // message row stride = 912B = 57 x 16B chunks

typedef unsigned int uint;
typedef unsigned short ushort;
typedef __bf16 bf16x8 __attribute__((ext_vector_type(8)));
typedef float  f32x4  __attribute__((ext_vector_type(4)));

__device__ __forceinline__ ushort f2bf(float f) {
    uint u = __builtin_bit_cast(uint, f);
    u += 0x7fffu + ((u >> 16) & 1u);     // RNE
    return (ushort)(u >> 16);
}
__device__ __forceinline__ float bfhi(uint w) {
    return __builtin_bit_cast(float, w & 0xffff0000u);
}
__device__ __forceinline__ float bflo(uint w) {
    return __builtin_bit_cast(float, w << 16);
}

// ---------------- pack kernels (run once per launch) ----------------

__global__ __launch_bounds__(256) void pack_tree(const float* __restrict__ tree,
                                                 ushort* __restrict__ tbuf) {
    const int r = blockIdx.x, t = threadIdx.x;
    if (t < 228) {
        uint p = 0;
        if (t < 225) {
            const float2 v = *(const float2*)&tree[(size_t)r * HIDDEN + 2 * t];
            p = (uint)f2bf(v.x) | ((uint)f2bf(v.y) << 16);
        }
        ((uint*)(tbuf + (size_t)r * MSTRIDE))[t] = p;
    }
}

__global__ __launch_bounds__(256) void pack_bonds(const float* __restrict__ fbonds,
                                                  ushort* __restrict__ Abuf) {
    const int r = blockIdx.x * 4 + (threadIdx.x >> 6);
    const int t = threadIdx.x & 63;
    if (r >= N_BONDS) return;
    ushort* row = Abuf + (size_t)r * KPAD;
    if (t < 40) row[t] = f2bf(fbonds[(size_t)r * 40 + t]);
    else        row[t] = 0;                    // cols 40..63 zero (first GEMM K=64)
    if (t < 16) row[496 + t] = 0;              // cols 496..511 zero
}

__global__ __launch_bounds__(256) void pack_atoms(const float* __restrict__ fatoms,
                                                  ushort* __restrict__ Aout) {
    const int r = blockIdx.x * 4 + (threadIdx.x >> 6);
    const int t = threadIdx.x & 63;
    if (r >= N_ATOMS) return;
    ushort* row = Aout + (size_t)r * KPAD;
    if (t < 40) row[t] = (t < 35) ? f2bf(fatoms[(size_t)r * 35 + t]) : (ushort)0;
    if (t < 16) row[496 + t] = 0;              // cols 496..511 zero
}

__global__ __launch_bounds__(256) void pack_w(const float* __restrict__ W_i,
                                              const float* __restrict__ W_h,
                                              const float* __restrict__ W_o,
                                              ushort* __restrict__ Wcat,
                                              ushort* __restrict__ Wocat) {
    const int n = blockIdx.x;  // 0..511
    for (int c = threadIdx.x; c < KPAD; c += 256) {
        float v = 0.0f, vo = 0.0f;
        if (n < HIDDEN) {
            if (c < 40)       v = W_i[(size_t)n * 40 + c];
            else if (c < 490) v = W_h[(size_t)n * HIDDEN + (c - 40)];
            if (c < 35)       vo = W_o[(size_t)n * 485 + c];
            else if (c >= 40 && c < 490) vo = W_o[(size_t)n * 485 + 35 + (c - 40)];
        }
        Wcat [(size_t)n * KPAD + c] = f2bf(v);
        Wocat[(size_t)n * KPAD + c] = f2bf(vo);
    }
}

// ---------------- gather: dst[r, 40..495] = sum_j concat(tree,gmsg)[g[r,j]] -------
__global__ __launch_bounds__(256) void gather_sum(const int* __restrict__ g,
                                                  const ushort* __restrict__ tbuf,
                                                  const ushort* __restrict__ gmsg,
                                                  ushort* __restrict__ dst, int nrows) {
    const int r = blockIdx.x * 4 + (threadIdx.x >> 6);
    const int lane = threadIdx.x & 63;
    if (r >= nrows) return;
    const int* gr = g + (size_t)r * MAX_NB;
    int idx[MAX_NB];
#pragma unroll
    for (int j = 0; j < MAX_NB; ++j) idx[j] = gr[j];
    if (lane >= 57) return;
    const int off = lane * 8;
    float acc[8] = {};
#pragma unroll
    for (int j = 0; j < MAX_NB; ++j) {
        const ushort* row = (idx[j] < N_MESS)
            ? tbuf + (size_t)idx[j] * MSTRIDE
            : gmsg + (size_t)(idx[j] - N_MESS) * MSTRIDE;
        const uint4 w = *(const uint4*)(row + off);
        acc[0] += bflo(w.x); acc[1] += bfhi(w.x);
        acc[2] += bflo(w.y); acc[3] += bfhi(w.y);
        acc[4] += bflo(w.z); acc[5] += bfhi(w.z);
        acc[6] += bflo(w.w); acc[7] += bfhi(w.w);
    }
    uint4 p;
    p.x = (uint)f2bf(acc[0]) | ((uint)f2bf(acc[1]) << 16);
    p.y = (uint)f2bf(acc[2]) | ((uint)f2bf(acc[3]) << 16);
    p.z = (uint)f2bf(acc[4]) | ((uint)f2bf(acc[5]) << 16);
    p.w = (uint)f2bf(acc[6]) | ((uint)f2bf(acc[7]) << 16);
    *(uint4*)(dst + (size_t)r * KPAD + 40 + off) = p;
}

// ---------------- MFMA GEMM: barrier-free, fragments direct from global ----------
// C[M x 450] = relu(A[M x K] · W[450 x K]^T (+bias))
// MODE 0: bf16 store to gmsg (+ zero pad cols). MODE 1: f32 atomicAdd to out,
// with equal-mol run merging (mol_ids is sorted).
// grid = (m_tiles, 4); block = 256 = 4 waves (2x2 of 64x64). No LDS, no barriers.
template <int MODE>
__global__ __launch_bounds__(256, 3) void mfma_gemm(
    const ushort* __restrict__ A, int M,
    const ushort* __restrict__ W, int K,
    const float* __restrict__ bias, const int* __restrict__ mol_ids,
    ushort* __restrict__ gout, float* __restrict__ aout) {
    const int lane = threadIdx.x & 63;
    const int wave = threadIdx.x >> 6;
    const int wm = (wave >> 1) * 64;
    const int wn = (wave & 1) * 64;
    const int m0 = blockIdx.x * 128;
    const int n0 = blockIdx.y * 128;
    const int lr = lane & 15;        // fragment row within 16
    const int lk = lane >> 4;        // k-chunk selector (8 elems each)

    // per-subtile global element offsets; k-step advances by +32 elements
    size_t aoff[4], woff[4];
#pragma unroll
    for (int s = 0; s < 4; ++s) {
        aoff[s] = (size_t)min(m0 + wm + s * 16 + lr, M - 1) * KPAD + lk * 8;
        woff[s] = (size_t)(n0 + wn + s * 16 + lr) * KPAD + lk * 8;
    }

    f32x4 acc[4][4];
#pragma unroll
    for (int i = 0; i < 4; ++i)
#pragma unroll
        for (int j = 0; j < 4; ++j) acc[i][j] = (f32x4){0.f, 0.f, 0.f, 0.f};

    bf16x8 a_cur[4], w_cur[4], a_nxt[4], w_nxt[4];
#pragma unroll
    for (int s = 0; s < 4; ++s) {
        a_cur[s] = *(const bf16x8*)&A[aoff[s]];
        w_cur[s] = *(const bf16x8*)&W[woff[s]];
    }

#pragma unroll 1
    for (int k0 = 0; k0 < K; k0 += 32) {
        // prefetch next step's fragments (clamped addr on last iter: always valid)
        const int kn = (k0 + 32 < K) ? k0 + 32 : 0;
#pragma unroll
        for (int s = 0; s < 4; ++s) {
            a_nxt[s] = *(const bf16x8*)&A[aoff[s] + kn];
            w_nxt[s] = *(const bf16x8*)&W[woff[s] + kn];
        }
#pragma unroll
        for (int mt = 0; mt < 4; ++mt)
#pragma unroll
            for (int nt = 0; nt < 4; ++nt)
                acc[mt][nt] = __builtin_amdgcn_mfma_f32_16x16x32_bf16(
                    a_cur[mt], w_cur[nt], acc[mt][nt], 0, 0, 0);
#pragma unroll
        for (int s = 0; s < 4; ++s) { a_cur[s] = a_nxt[s]; w_cur[s] = w_nxt[s]; }
    }

    const int col_l = lane & 15;
    const int rbase = (lane >> 4) * 4;
#pragma unroll
    for (int mt = 0; mt < 4; ++mt) {
        const int mbase = m0 + wm + mt * 16 + rbase;
        int mol[4];
        if (MODE == 1) {
#pragma unroll
            for (int reg = 0; reg < 4; ++reg)
                mol[reg] = mol_ids[min(mbase + reg, M - 1)];
        }
#pragma unroll
        for (int nt = 0; nt < 4; ++nt) {
            const int n = n0 + wn + nt * 16 + col_l;
            if (MODE == 0) {
#pragma unroll
                for (int reg = 0; reg < 4; ++reg) {
                    const int m = mbase + reg;
                    if (m >= M) continue;
                    if (n < HIDDEN)
                        gout[(size_t)m * MSTRIDE + n] = f2bf(fmaxf(acc[mt][nt][reg], 0.0f));
                    else if (n < MSTRIDE)
                        gout[(size_t)m * MSTRIDE + n] = 0;  // keep pad cols zero
                }
            } else {
                if (n >= HIDDEN) continue;
                const float b = bias[n];
                float run = 0.0f;
                int cur = mol[0];
#pragma unroll
                for (int reg = 0; reg < 4; ++reg) {
                    const float v = (mbase + reg < M)
                        ? fmaxf(acc[mt][nt][reg] + b, 0.0f) : 0.0f;
                    if (mol[reg] != cur) {
                        atomicAdd(&aout[(size_t)cur * HIDDEN + n], run);
                        cur = mol[reg];
                        run = 0.0f;
                    }
                    run += v;
                }
                atomicAdd(&aout[(size_t)cur * HIDDEN + n], run);
            }
        }
    }
}

// ---------------- molecule mean ----------------
__global__ __launch_bounds__(256) void count_atoms(const int* __restrict__ mol_ids,
                                                   float* __restrict__ counts) {
    const int a = blockIdx.x * 256 + threadIdx.x;
    if (a < N_ATOMS) atomicAdd(&counts[mol_ids[a]], 1.0f);
}
__global__ __launch_bounds__(256) void div_counts(float* __restrict__ out,
                                                  const float* __restrict__ counts) {
    const int i = blockIdx.x * 256 + threadIdx.x;
    if (i < N_MOLS * HIDDEN) out[i] = out[i] / counts[i / HIDDEN];
}

extern "C" void kernel_launch(void* const* d_in, const int* in_sizes, int n_in,
                              void* d_out, int out_size, void* d_ws, size_t ws_size,
                              hipStream_t stream) {
    const float* fatoms  = (const float*)d_in[0];
    const float* fbonds  = (const float*)d_in[1];
    const int*   agraph  = (const int*)d_in[2];
    const int*   bgraph  = (const int*)d_in[3];
    const int*   mol_ids = (const int*)d_in[4];
    const float* tree    = (const float*)d_in[6];
    const float* W_i     = (const float*)d_in[7];
    const float* W_h     = (const float*)d_in[8];
    const float* W_o     = (const float*)d_in[9];
    const float* b_o     = (const float*)d_in[10];
    float* out = (float*)d_out;

    ushort* Abuf  = (ushort*)d_ws;                       // 40000 x 512
    ushort* Aout  = Abuf  + (size_t)N_BONDS * KPAD;      // 20000 x 512
    ushort* gmsg  = Aout  + (size_t)N_ATOMS * KPAD;      // 40000 x 456
    ushort* tbuf  = gmsg  + (size_t)N_BONDS * MSTRIDE;   // 16000 x 456
    ushort* Wcat  = tbuf  + (size_t)N_MESS  * MSTRIDE;   // 512 x 512
    ushort* Wocat = Wcat  + (size_t)KPAD * KPAD;         // 512 x 512
    float*  counts = (float*)(Wocat + (size_t)KPAD * KPAD);

    (void)hipMemsetAsync(d_out, 0, (size_t)N_MOLS * HIDDEN * sizeof(float), stream);
    (void)hipMemsetAsync(counts, 0, N_MOLS * sizeof(float), stream);

    const dim3 blk(256);
    pack_tree <<<N_MESS, blk, 0, stream>>>(tree, tbuf);
    pack_bonds<<<(N_BONDS + 3) / 4, blk, 0, stream>>>(fbonds, Abuf);
    pack_atoms<<<(N_ATOMS + 3) / 4, blk, 0, stream>>>(fatoms, Aout);
    pack_w    <<<KPAD, blk, 0, stream>>>(W_i, W_h, W_o, Wcat, Wocat);

    const dim3 gB((N_BONDS + 127) / 128, 4);
    const dim3 gA((N_ATOMS + 127) / 128, 4);

    // gmsg = relu(fbonds @ W_i^T): nei cols 40..63 are zero, so K=64 suffices
    mfma_gemm<0><<<gB, blk, 0, stream>>>(Abuf, N_BONDS, Wcat, 64,
                                         nullptr, nullptr, gmsg, nullptr);
    for (int it = 0; it < 5; ++it) {
        gather_sum<<<(N_BONDS + 3) / 4, blk, 0, stream>>>(bgraph, tbuf, gmsg,
                                                          Abuf, N_BONDS);
        mfma_gemm<0><<<gB, blk, 0, stream>>>(Abuf, N_BONDS, Wcat, KPAD,
                                             nullptr, nullptr, gmsg, nullptr);
    }
    gather_sum<<<(N_ATOMS + 3) / 4, blk, 0, stream>>>(agraph, tbuf, gmsg,
                                                      Aout, N_ATOMS);
    mfma_gemm<1><<<gA, blk, 0, stream>>>(Aout, N_ATOMS, Wocat, KPAD,
                                         b_o, mol_ids, nullptr, out);

    count_atoms<<<(N_ATOMS + 255) / 256, blk, 0, stream>>>(mol_ids, counts);
    div_counts <<<(N_MOLS * HIDDEN + 255) / 256, blk, 0, stream>>>(out, counts);
}